// Round 1
// baseline (72.607 us; speedup 1.0000x reference)
//
#include <hip/hip_runtime.h>

#define S 128
#define DFEAT 150528
#define BK 64
#define NCHUNK (DFEAT / BK)   // 2352
#define GRIDG 256

typedef short short8 __attribute__((ext_vector_type(8)));
typedef float f32x4 __attribute__((ext_vector_type(4)));

__device__ __forceinline__ unsigned short f2bf(float f) {
    unsigned u = __builtin_bit_cast(unsigned, f);
    unsigned r = (u + 0x7FFFu + ((u >> 16) & 1u)) >> 16;   // RNE
    return (unsigned short)r;
}

__device__ __forceinline__ unsigned long long pack4(float4 v) {
    return (unsigned long long)f2bf(v.x)
         | ((unsigned long long)f2bf(v.y) << 16)
         | ((unsigned long long)f2bf(v.z) << 32)
         | ((unsigned long long)f2bf(v.w) << 48);
}

// K1: partial Gram over this block's K-chunks + partial row sum-of-squares.
// A = clip2 (matrix rows, x), B = clip1 (matrix cols, y).
__global__ __launch_bounds__(512, 1) void k1_gram(
    const float* __restrict__ A,
    const float* __restrict__ B,
    float* __restrict__ gramPart,   // [G][128*128]
    float* __restrict__ sqBuf,      // [256]: [0..127]=||a_i||^2, [128..255]=||b_j||^2
    int G)
{
    __shared__ alignas(16) char lds[32768];  // As bf16[128][64] @0, Bs @16384

    const int t  = threadIdx.x;
    const int g  = blockIdx.x;
    const int r  = t >> 2;      // row this thread stages (0..127)
    const int q4 = t & 3;

    const float4* __restrict__ arow = (const float4*)(A + (size_t)r * DFEAT);
    const float4* __restrict__ brow = (const float4*)(B + (size_t)r * DFEAT);

    const int w    = t >> 6;
    const int lane = t & 63;
    const int wr   = w >> 2;          // 0..1  (64 rows each)
    const int wc   = w & 3;           // 0..3  (32 cols each)
    const int lrow = lane & 15;
    const int lk   = (lane >> 4) * 8; // k offset within 32-wide MFMA step

    f32x4 acc[4][2];
    #pragma unroll
    for (int i = 0; i < 4; i++)
        #pragma unroll
        for (int j = 0; j < 2; j++) {
            f32x4 z = {0.f, 0.f, 0.f, 0.f};
            acc[i][j] = z;
        }

    float sqa = 0.f, sqb = 0.f;

    float4 va[4], vb[4];
    int c = g;
    #pragma unroll
    for (int it = 0; it < 4; it++) {
        int idx = c * 16 + it * 4 + q4;
        va[it] = arow[idx];
        vb[it] = brow[idx];
    }

    while (c < NCHUNK) {
        __syncthreads();   // previous MFMA phase done reading LDS
        // stage chunk c (registers -> bf16 -> swizzled LDS) + sq accumulate
        #pragma unroll
        for (int it = 0; it < 4; it++) {
            int fq   = it * 4 + q4;
            int addr = (r * 128 + fq * 8) ^ ((r & 7) << 4);
            float4 v = va[it];
            *(unsigned long long*)(lds + addr) = pack4(v);
            sqa += v.x*v.x + v.y*v.y + v.z*v.z + v.w*v.w;
            v = vb[it];
            *(unsigned long long*)(lds + 16384 + addr) = pack4(v);
            sqb += v.x*v.x + v.y*v.y + v.z*v.z + v.w*v.w;
        }
        // prefetch next chunk into registers (in flight during MFMA phase)
        int cn = c + G;
        if (cn < NCHUNK) {
            #pragma unroll
            for (int it = 0; it < 4; it++) {
                int idx = cn * 16 + it * 4 + q4;
                va[it] = arow[idx];
                vb[it] = brow[idx];
            }
        }
        __syncthreads();   // LDS tile ready
        #pragma unroll
        for (int kk = 0; kk < 2; kk++) {
            short8 bfrag[2], afrag[4];
            #pragma unroll
            for (int tn = 0; tn < 2; tn++) {
                int n   = wc * 32 + tn * 16 + lrow;
                int off = (n * 128 + (kk * 32 + lk) * 2) ^ ((n & 7) << 4);
                bfrag[tn] = *(const short8*)(lds + 16384 + off);
            }
            #pragma unroll
            for (int tm = 0; tm < 4; tm++) {
                int m   = wr * 64 + tm * 16 + lrow;
                int off = (m * 128 + (kk * 32 + lk) * 2) ^ ((m & 7) << 4);
                afrag[tm] = *(const short8*)(lds + off);
            }
            #pragma unroll
            for (int tm = 0; tm < 4; tm++)
                #pragma unroll
                for (int tn = 0; tn < 2; tn++)
                    acc[tm][tn] = __builtin_amdgcn_mfma_f32_16x16x32_bf16(
                        afrag[tm], bfrag[tn], acc[tm][tn], 0, 0, 0);
        }
        c = cn;
    }

    // write partial gram tile; C/D layout: col=lane&15, row=(lane>>4)*4+reg
    float* gp = gramPart + (size_t)g * (S * S);
    const int crow = (lane >> 4) * 4;
    const int ccol = lane & 15;
    #pragma unroll
    for (int tm = 0; tm < 4; tm++) {
        #pragma unroll
        for (int tn = 0; tn < 2; tn++) {
            int row0 = wr * 64 + tm * 16 + crow;
            int col  = wc * 32 + tn * 16 + ccol;
            #pragma unroll
            for (int rg = 0; rg < 4; rg++)
                gp[(size_t)(row0 + rg) * S + col] = acc[tm][tn][rg];
        }
    }

    // reduce sq over the 4 lanes sharing a row, then accumulate globally
    sqa += __shfl_down(sqa, 2); sqa += __shfl_down(sqa, 1);
    sqb += __shfl_down(sqb, 2); sqb += __shfl_down(sqb, 1);
    if (q4 == 0) {
        atomicAdd(&sqBuf[r], sqa);
        atomicAdd(&sqBuf[128 + r], sqb);
    }
}

// K2: reduce G partials per matrix entry, accumulate into diagonal bins.
__global__ void k2_reduce(const float* __restrict__ gramPart,
                          float* __restrict__ diag, int G)
{
    int e = blockIdx.x * 256 + threadIdx.x;   // 0..16383
    float s0 = 0.f, s1 = 0.f, s2 = 0.f, s3 = 0.f;
    int g = 0;
    for (; g + 4 <= G; g += 4) {
        s0 += gramPart[(size_t)(g + 0) * 16384 + e];
        s1 += gramPart[(size_t)(g + 1) * 16384 + e];
        s2 += gramPart[(size_t)(g + 2) * 16384 + e];
        s3 += gramPart[(size_t)(g + 3) * 16384 + e];
    }
    for (; g < G; g++) s0 += gramPart[(size_t)g * 16384 + e];
    float s = (s0 + s1) + (s2 + s3);
    int i = e >> 7, j = e & 127;
    atomicAdd(&diag[127 - i + j], s);   // col = (S-1) - i + j
}

// K3: combine diag gram sums with sq-norm terms -> 129 outputs.
__global__ void k3_out(const float* __restrict__ sqBuf,
                       const float* __restrict__ diag,
                       float* __restrict__ out)
{
    int o = threadIdx.x;
    if (o >= 129) return;
    int d   = o - 64;
    int ad  = d < 0 ? -d : d;
    int cnt = 128 - ad;
    int i0  = d < 0 ? -d : 0;
    float sq = 0.f;
    for (int tt = 0; tt < cnt; tt++) {
        int i = i0 + tt;
        sq += sqBuf[i] + sqBuf[128 + i + d];
    }
    float gv = diag[63 + o];
    out[o] = -((sq - 2.f * gv) * (1.0f / (float)DFEAT)) * 1e13f / (float)cnt;
}

extern "C" void kernel_launch(void* const* d_in, const int* in_sizes, int n_in,
                              void* d_out, int out_size, void* d_ws, size_t ws_size,
                              hipStream_t stream) {
    const float* clip1 = (const float*)d_in[0];  // b: matrix cols (y)
    const float* clip2 = (const float*)d_in[1];  // a: matrix rows (x)
    float* out = (float*)d_out;

    int G = GRIDG;
    const size_t per = (size_t)S * S * sizeof(float);  // 64 KiB per partial
    while (G > 1 && (size_t)G * per + 8192 > ws_size) G >>= 1;

    float* gramPart = (float*)d_ws;
    float* sqBuf    = (float*)((char*)d_ws + (size_t)G * per);
    float* diag     = sqBuf + 256;

    hipMemsetAsync(sqBuf, 0, 4096, stream);  // zero sq (1KB) + diag (1020B)
    k1_gram<<<dim3(G), dim3(512), 0, stream>>>(clip2, clip1, gramPart, sqBuf, G);
    k2_reduce<<<dim3(64), dim3(256), 0, stream>>>(gramPart, diag, G);
    k3_out<<<dim3(1), dim3(256), 0, stream>>>(sqBuf, diag, out);
}